// Round 20
// baseline (25.739 us; speedup 1.0000x reference)
//
#include <hip/hip_runtime.h>

// FutureEncoder as banded flash-attention on MFMA (bf16 split-precision).
// out[b,t,:] = softmax_j(x[t]·x[t+1+j]) · x[t+1+j], j in [0,16), fp32 I/O.
//
// Round 20 = R19 + batched-issue QK loads (miss-level parallelism).
// Model from R19's delta: plateau = L2-miss traffic (~85MB) at ~3.5 TB/s
// fabric service; rate is concurrency-limited (compiler at VGPR=64 keeps
// only ~2-4 loads/wave in flight). Restructure: issue ALL 8 Q + 16 K
// dwordx4 loads first (24 outstanding/wave), then stage K->LDS (batch
// completion), then splits+MFMA. Grid caps occupancy at 16 waves/CU =
// exactly the 128-VGPR point, so the load buffers are occupancy-free.

typedef float f32x4 __attribute__((ext_vector_type(4)));
typedef unsigned int u32;
typedef u32 u32x4 __attribute__((ext_vector_type(4)));
typedef short bf16x8 __attribute__((ext_vector_type(8)));

namespace {
constexpr int kB = 2, kS = 4096, kH = 1024;
constexpr int kWaves = 8;                    // 512 threads
constexpr int kTilesT = 16;                  // t's per block
constexpr int kBlocks = kB * kS / kTilesT;   // 512 -> 2 blocks/CU
constexpr int kXCD = 8;
constexpr int kHW = kH / kWaves;             // 128 h-cols per wave
}

__device__ __forceinline__ u32 f32u(float x){ return __builtin_bit_cast(u32, x); }
__device__ __forceinline__ float uf32(u32 x){ return __builtin_bit_cast(float, x); }
__device__ __forceinline__ u32 pkbf(float a, float b){ return (f32u(b)&0xFFFF0000u)|(f32u(a)>>16); }

struct Frag2 { bf16x8 hi, lo; };
__device__ __forceinline__ Frag2 split2(float4 u, float4 v) {
  float fu[8] = {u.x,u.y,u.z,u.w,v.x,v.y,v.z,v.w};
  u32 hw[4], lw[4];
#pragma unroll
  for (int i = 0; i < 4; ++i) {
    float a = fu[2*i], b = fu[2*i+1];
    u32 ua = f32u(a), ub = f32u(b);
    hw[i] = (ub & 0xFFFF0000u) | (ua >> 16);
    float la = a - uf32(ua & 0xFFFF0000u);
    float lb = b - uf32(ub & 0xFFFF0000u);
    lw[i] = (f32u(lb) & 0xFFFF0000u) | (f32u(la) >> 16);
  }
  Frag2 r;
  u32x4 h = {hw[0],hw[1],hw[2],hw[3]}, l = {lw[0],lw[1],lw[2],lw[3]};
  r.hi = __builtin_bit_cast(bf16x8, h);
  r.lo = __builtin_bit_cast(bf16x8, l);
  return r;
}

#define MFMA(A,B,C) __builtin_amdgcn_mfma_f32_16x16x32_bf16((A),(B),(C),0,0,0)

__global__ __launch_bounds__(512, 4)
void fenc_mfma(const float* __restrict__ x, float* __restrict__ out) {
  __shared__ f32x4 red[kWaves][2][64];           // 16 KB: S^T partials
  __shared__ __align__(16) unsigned short kst[kWaves][32 * 128];  // 64 KB: bf16 K-stage
  const int lane = (int)(threadIdx.x & 63), wid = (int)(threadIdx.x >> 6);
  const int g = lane >> 4, c = lane & 15;

  // XCD strip swizzle (512 % 8 == 0 -> bijective)
  const int vb  = (int)(blockIdx.x % kXCD)*(kBlocks/kXCD) + (int)(blockIdx.x / kXCD);
  const int t0g = vb * kTilesT;
  const int b   = t0g / kS, t0 = t0g % kS;
  const float* __restrict__ xb = x + (size_t)b*kS*kH;
  float* __restrict__ ob = out + (size_t)b*kS*kH;
  const int hw0 = kHW * wid;

  const int ra = (t0 + 1 + c  < kS) ? (t0 + 1 + c)  : (kS - 1);
  const int rb = (t0 + 17 + c < kS) ? (t0 + 17 + c) : (kS - 1);
  const float* qp  = xb + (size_t)(t0 + c)*kH + hw0;
  const float* kpa = xb + (size_t)ra*kH + hw0;
  const float* kpb = xb + (size_t)rb*kH + hw0;
  unsigned short* ks_base = &kst[wid][0];

  // ---- phase 0/1: issue ALL QK loads (24 dwordx4 outstanding/wave) ----
  float4 qv[4][2], av[4][2], bv[4][2];
#pragma unroll
  for (int ks = 0; ks < 4; ++ks) {
    const int off = ks*32 + g*8;
    qv[ks][0] = *(const float4*)(qp + off);
    qv[ks][1] = *(const float4*)(qp + off + 4);
  }
#pragma unroll
  for (int ks = 0; ks < 4; ++ks) {
    const int off = ks*32 + g*8;
    av[ks][0] = *(const float4*)(kpa + off);
    av[ks][1] = *(const float4*)(kpa + off + 4);
    bv[ks][0] = *(const float4*)(kpb + off);
    bv[ks][1] = *(const float4*)(kpb + off + 4);
  }

  // ---- phase 2: stage K rows to LDS as bf16 (batch completion of K) ----
  // row w (0..31): element index = w*128 + (m ^ xw16), xw16 = ((w&7)<<3)^((w>>3)<<4)
  const int wA = c,      xA = ((wA & 7) << 3) ^ ((wA >> 3) << 4);
  const int wB = 16 + c, xB = ((wB & 7) << 3) ^ ((wB >> 3) << 4);
#pragma unroll
  for (int ks = 0; ks < 4; ++ks) {
    const int off = ks*32 + g*8;
    u32x4 pkA = { pkbf(av[ks][0].x,av[ks][0].y), pkbf(av[ks][0].z,av[ks][0].w),
                  pkbf(av[ks][1].x,av[ks][1].y), pkbf(av[ks][1].z,av[ks][1].w) };
    u32x4 pkB = { pkbf(bv[ks][0].x,bv[ks][0].y), pkbf(bv[ks][0].z,bv[ks][0].w),
                  pkbf(bv[ks][1].x,bv[ks][1].y), pkbf(bv[ks][1].z,bv[ks][1].w) };
    *(u32x4*)(ks_base + wA*128 + (off ^ xA)) = pkA;
    *(u32x4*)(ks_base + wB*128 + (off ^ xB)) = pkB;
  }

  // ---- phase 3: splits + MFMA (6 independent chains, depth 4) ----
  f32x4 aHH = {0.f,0.f,0.f,0.f}, aHL = aHH, aLH = aHH;
  f32x4 bHH = aHH, bHL = aHH, bLH = aHH;
  __builtin_amdgcn_s_setprio(1);
#pragma unroll
  for (int ks = 0; ks < 4; ++ks) {
    Frag2 fq = split2(qv[ks][0], qv[ks][1]);
    Frag2 fa = split2(av[ks][0], av[ks][1]);
    Frag2 fb = split2(bv[ks][0], bv[ks][1]);
    aHH = MFMA(fa.hi, fq.hi, aHH);
    aHL = MFMA(fa.hi, fq.lo, aHL);
    aLH = MFMA(fa.lo, fq.hi, aLH);
    bHH = MFMA(fb.hi, fq.hi, bHH);
    bHL = MFMA(fb.hi, fq.lo, bHL);
    bLH = MFMA(fb.lo, fq.hi, bLH);
  }
  __builtin_amdgcn_s_setprio(0);
  f32x4 accA = (aHH + aHL) + aLH;
  f32x4 accB = (bHH + bHL) + bLH;

  // ---- cross-wave reduce of S^T partials ----
  red[wid][0][lane] = accA;
  red[wid][1][lane] = accB;
  __syncthreads();
#pragma unroll
  for (int w = 0; w < kWaves; ++w) {
    if (w != wid) {
      accA += red[w][0][lane];
      accB += red[w][1][lane];
    }
  }

  // ---- softmax (per lane: all 32 windows of t = t0+c) ----
  float p[2][4];
  float vmax = -1e30f;
#pragma unroll
  for (int T = 0; T < 2; ++T)
#pragma unroll
    for (int r = 0; r < 4; ++r) {
      const int w = 16*T + 4*g + r;
      const bool val = (w >= c) && (w < c + 16) && (t0 + 1 + w < kS);
      const float sv = val ? (T ? accB[r] : accA[r]) : -1e30f;
      p[T][r] = sv;
      vmax = fmaxf(vmax, sv);
    }
  vmax = fmaxf(vmax, __shfl_xor(vmax, 16, 64));
  vmax = fmaxf(vmax, __shfl_xor(vmax, 32, 64));
  float psum = 0.f;
#pragma unroll
  for (int T = 0; T < 2; ++T)
#pragma unroll
    for (int r = 0; r < 4; ++r) {
      const int w = 16*T + 4*g + r;
      const bool val = (w >= c) && (w < c + 16) && (t0 + 1 + w < kS);
      const float e = val ? __expf(p[T][r] - vmax) : 0.f;
      p[T][r] = e;
      psum += e;
    }
  psum += __shfl_xor(psum, 16, 64);
  psum += __shfl_xor(psum, 32, 64);
  const float inv = (psum > 0.f) ? (1.f / psum) : 0.f;
#pragma unroll
  for (int T = 0; T < 2; ++T)
#pragma unroll
    for (int r = 0; r < 4; ++r) p[T][r] *= inv;

  // ---- build P^T A-frag: lane needs P[t=c][w = 8g+i], i=0..7 ----
  const int se = (g & 1)*32 + c, so = se + 16;
  float slot[8];
#pragma unroll
  for (int r = 0; r < 4; ++r) {
    const float e0 = __shfl(p[0][r], se, 64), e1 = __shfl(p[1][r], se, 64);
    const float o0 = __shfl(p[0][r], so, 64), o1 = __shfl(p[1][r], so, 64);
    slot[r]     = (g >> 1) ? e1 : e0;
    slot[4 + r] = (g >> 1) ? o1 : o0;
  }
  u32x4 pw = { pkbf(slot[0],slot[1]), pkbf(slot[2],slot[3]),
               pkbf(slot[4],slot[5]), pkbf(slot[6],slot[7]) };
  const bf16x8 pa = __builtin_bit_cast(bf16x8, pw);

  // ---- PV: V-frags from this wave's OWN LDS stage (no global reads) ----
  f32x4 o[8];
  __builtin_amdgcn_s_setprio(1);
#pragma unroll
  for (int nt = 0; nt < 8; ++nt) {
    const int m = 16*nt + c;
    u32 vwj[4];
#pragma unroll
    for (int jj = 0; jj < 4; ++jj) {
      const int w0 = 8*g + 2*jj, w1 = w0 + 1;
      const int x0 = (((w0 & 7) << 3) ^ (g << 4));
      const int x1 = (((w1 & 7) << 3) ^ (g << 4));
      const u32 lo = ks_base[w0*128 + (m ^ x0)];
      const u32 hi = ks_base[w1*128 + (m ^ x1)];
      vwj[jj] = lo | (hi << 16);
    }
    u32x4 vw = { vwj[0], vwj[1], vwj[2], vwj[3] };
    const bf16x8 vfrag = __builtin_bit_cast(bf16x8, vw);
    f32x4 z = {0.f,0.f,0.f,0.f};
    o[nt] = MFMA(pa, vfrag, z);
  }
  __builtin_amdgcn_s_setprio(0);

  // ---- store (non-temporal: output is never re-read) ----
  float* orow[4];
#pragma unroll
  for (int r = 0; r < 4; ++r)
    orow[r] = ob + (size_t)(t0 + 4*g + r)*kH + hw0 + c;
#pragma unroll
  for (int nt = 0; nt < 8; ++nt)
#pragma unroll
    for (int r = 0; r < 4; ++r)
      __builtin_nontemporal_store(o[nt][r], &orow[r][16*nt]);
}

extern "C" void kernel_launch(void* const* d_in, const int* in_sizes, int n_in,
                              void* d_out, int out_size, void* d_ws, size_t ws_size,
                              hipStream_t stream) {
  const float* x = (const float*)d_in[0];
  float* out = (float*)d_out;
  hipLaunchKernelGGL(fenc_mfma, dim3(kBlocks), dim3(512), 0, stream, x, out);
}

// Round 21
// 24.294 us; speedup vs baseline: 1.0595x; 1.0595x over previous
//
#include <hip/hip_runtime.h>

// FutureEncoder as banded flash-attention on MFMA (bf16 split-precision).
// out[b,t,:] = softmax_j(x[t]·x[t+1+j]) · x[t+1+j], j in [0,16), fp32 I/O.
//
// Round 21 = REVERT to R19 (best measured: 24.3us). R20's batched-issue
// experiment was neutral-to-negative (25.7) -> the load pipeline was not
// concurrency-limited; restored the interleaved load/stage/MFMA k-loop.
// Structure: block (512thr, 8 waves) owns 16 t's; swapped QK^T k-split over
// H (waves own 128-col slices); split-bf16 scores (hi*hi+hi*lo+lo*hi);
// exact in-lane softmax; V-fragments re-read from the wave's OWN bf16 K
// stage in LDS (zero global V traffic); non-temporal output stores.

typedef float f32x4 __attribute__((ext_vector_type(4)));
typedef unsigned int u32;
typedef u32 u32x4 __attribute__((ext_vector_type(4)));
typedef short bf16x8 __attribute__((ext_vector_type(8)));

namespace {
constexpr int kB = 2, kS = 4096, kH = 1024;
constexpr int kWaves = 8;                    // 512 threads
constexpr int kTilesT = 16;                  // t's per block
constexpr int kBlocks = kB * kS / kTilesT;   // 512 -> 2 blocks/CU
constexpr int kXCD = 8;
constexpr int kHW = kH / kWaves;             // 128 h-cols per wave
}

__device__ __forceinline__ u32 f32u(float x){ return __builtin_bit_cast(u32, x); }
__device__ __forceinline__ float uf32(u32 x){ return __builtin_bit_cast(float, x); }
__device__ __forceinline__ u32 pkbf(float a, float b){ return (f32u(b)&0xFFFF0000u)|(f32u(a)>>16); }

struct Frag2 { bf16x8 hi, lo; };
__device__ __forceinline__ Frag2 split2(float4 u, float4 v) {
  float fu[8] = {u.x,u.y,u.z,u.w,v.x,v.y,v.z,v.w};
  u32 hw[4], lw[4];
#pragma unroll
  for (int i = 0; i < 4; ++i) {
    float a = fu[2*i], b = fu[2*i+1];
    u32 ua = f32u(a), ub = f32u(b);
    hw[i] = (ub & 0xFFFF0000u) | (ua >> 16);
    float la = a - uf32(ua & 0xFFFF0000u);
    float lb = b - uf32(ub & 0xFFFF0000u);
    lw[i] = (f32u(lb) & 0xFFFF0000u) | (f32u(la) >> 16);
  }
  Frag2 r;
  u32x4 h = {hw[0],hw[1],hw[2],hw[3]}, l = {lw[0],lw[1],lw[2],lw[3]};
  r.hi = __builtin_bit_cast(bf16x8, h);
  r.lo = __builtin_bit_cast(bf16x8, l);
  return r;
}

#define MFMA(A,B,C) __builtin_amdgcn_mfma_f32_16x16x32_bf16((A),(B),(C),0,0,0)

__global__ __launch_bounds__(512, 4)
void fenc_mfma(const float* __restrict__ x, float* __restrict__ out) {
  __shared__ f32x4 red[kWaves][2][64];           // 16 KB: S^T partials
  __shared__ __align__(16) unsigned short kst[kWaves][32 * 128];  // 64 KB: bf16 K-stage
  const int lane = (int)(threadIdx.x & 63), wid = (int)(threadIdx.x >> 6);
  const int g = lane >> 4, c = lane & 15;

  // XCD strip swizzle (512 % 8 == 0 -> bijective)
  const int vb  = (int)(blockIdx.x % kXCD)*(kBlocks/kXCD) + (int)(blockIdx.x / kXCD);
  const int t0g = vb * kTilesT;
  const int b   = t0g / kS, t0 = t0g % kS;
  const float* __restrict__ xb = x + (size_t)b*kS*kH;
  float* __restrict__ ob = out + (size_t)b*kS*kH;
  const int hw0 = kHW * wid;

  // ---- QK^T (swapped: A = K windows, B = Q) + K->LDS bf16 stage ----
  const int ra = (t0 + 1 + c  < kS) ? (t0 + 1 + c)  : (kS - 1);
  const int rb = (t0 + 17 + c < kS) ? (t0 + 17 + c) : (kS - 1);
  const float* qp  = xb + (size_t)(t0 + c)*kH + hw0;
  const float* kpa = xb + (size_t)ra*kH + hw0;
  const float* kpb = xb + (size_t)rb*kH + hw0;
  unsigned short* ks_base = &kst[wid][0];

  // row w (0..31) of the stage holds x[t0+1+w][hw0..hw0+128) as bf16.
  // element index = w*128 + (m ^ xw16), xw16 = ((w&7)<<3) ^ ((w>>3)<<4).
  const int wA = c,      xA = ((wA & 7) << 3) ^ ((wA >> 3) << 4);
  const int wB = 16 + c, xB = ((wB & 7) << 3) ^ ((wB >> 3) << 4);

  f32x4 aHH = {0.f,0.f,0.f,0.f}, aHL = aHH, aLH = aHH;
  f32x4 bHH = aHH, bHL = aHH, bLH = aHH;
  __builtin_amdgcn_s_setprio(1);
#pragma unroll
  for (int ks = 0; ks < 4; ++ks) {
    const int off = ks*32 + g*8;
    float4 q0 = *(const float4*)(qp  + off), q1 = *(const float4*)(qp  + off + 4);
    float4 a0 = *(const float4*)(kpa + off), a1 = *(const float4*)(kpa + off + 4);
    float4 b0 = *(const float4*)(kpb + off), b1 = *(const float4*)(kpb + off + 4);

    // Stage K rows to LDS (bf16 truncation == the old V packing)
    u32x4 pkA = { pkbf(a0.x,a0.y), pkbf(a0.z,a0.w), pkbf(a1.x,a1.y), pkbf(a1.z,a1.w) };
    u32x4 pkB = { pkbf(b0.x,b0.y), pkbf(b0.z,b0.w), pkbf(b1.x,b1.y), pkbf(b1.z,b1.w) };
    *(u32x4*)(ks_base + wA*128 + (off ^ xA)) = pkA;
    *(u32x4*)(ks_base + wB*128 + (off ^ xB)) = pkB;

    Frag2 fq = split2(q0, q1), fa = split2(a0, a1), fb = split2(b0, b1);
    aHH = MFMA(fa.hi, fq.hi, aHH);
    aHL = MFMA(fa.hi, fq.lo, aHL);
    aLH = MFMA(fa.lo, fq.hi, aLH);
    bHH = MFMA(fb.hi, fq.hi, bHH);
    bHL = MFMA(fb.hi, fq.lo, bHL);
    bLH = MFMA(fb.lo, fq.hi, bLH);
  }
  __builtin_amdgcn_s_setprio(0);
  f32x4 accA = (aHH + aHL) + aLH;
  f32x4 accB = (bHH + bHL) + bLH;

  // ---- cross-wave reduce of S^T partials ----
  red[wid][0][lane] = accA;
  red[wid][1][lane] = accB;
  __syncthreads();
#pragma unroll
  for (int w = 0; w < kWaves; ++w) {
    if (w != wid) {
      accA += red[w][0][lane];
      accB += red[w][1][lane];
    }
  }

  // ---- softmax (per lane: all 32 windows of t = t0+c) ----
  float p[2][4];
  float vmax = -1e30f;
#pragma unroll
  for (int T = 0; T < 2; ++T)
#pragma unroll
    for (int r = 0; r < 4; ++r) {
      const int w = 16*T + 4*g + r;
      const bool val = (w >= c) && (w < c + 16) && (t0 + 1 + w < kS);
      const float sv = val ? (T ? accB[r] : accA[r]) : -1e30f;
      p[T][r] = sv;
      vmax = fmaxf(vmax, sv);
    }
  vmax = fmaxf(vmax, __shfl_xor(vmax, 16, 64));
  vmax = fmaxf(vmax, __shfl_xor(vmax, 32, 64));
  float psum = 0.f;
#pragma unroll
  for (int T = 0; T < 2; ++T)
#pragma unroll
    for (int r = 0; r < 4; ++r) {
      const int w = 16*T + 4*g + r;
      const bool val = (w >= c) && (w < c + 16) && (t0 + 1 + w < kS);
      const float e = val ? __expf(p[T][r] - vmax) : 0.f;
      p[T][r] = e;
      psum += e;
    }
  psum += __shfl_xor(psum, 16, 64);
  psum += __shfl_xor(psum, 32, 64);
  const float inv = (psum > 0.f) ? (1.f / psum) : 0.f;
#pragma unroll
  for (int T = 0; T < 2; ++T)
#pragma unroll
    for (int r = 0; r < 4; ++r) p[T][r] *= inv;

  // ---- build P^T A-frag: lane needs P[t=c][w = 8g+i], i=0..7 ----
  const int se = (g & 1)*32 + c, so = se + 16;
  float slot[8];
#pragma unroll
  for (int r = 0; r < 4; ++r) {
    const float e0 = __shfl(p[0][r], se, 64), e1 = __shfl(p[1][r], se, 64);
    const float o0 = __shfl(p[0][r], so, 64), o1 = __shfl(p[1][r], so, 64);
    slot[r]     = (g >> 1) ? e1 : e0;
    slot[4 + r] = (g >> 1) ? o1 : o0;
  }
  u32x4 pw = { pkbf(slot[0],slot[1]), pkbf(slot[2],slot[3]),
               pkbf(slot[4],slot[5]), pkbf(slot[6],slot[7]) };
  const bf16x8 pa = __builtin_bit_cast(bf16x8, pw);

  // ---- PV: V-frags from this wave's OWN LDS stage (no global reads) ----
  // lane (g,c), tile nt: needs V[w = 8g+i][m = 16nt+c], i = 0..7.
  f32x4 o[8];
  __builtin_amdgcn_s_setprio(1);
#pragma unroll
  for (int nt = 0; nt < 8; ++nt) {
    const int m = 16*nt + c;
    u32 vwj[4];
#pragma unroll
    for (int jj = 0; jj < 4; ++jj) {
      const int w0 = 8*g + 2*jj, w1 = w0 + 1;
      const int x0 = (((w0 & 7) << 3) ^ (g << 4));
      const int x1 = (((w1 & 7) << 3) ^ (g << 4));
      const u32 lo = ks_base[w0*128 + (m ^ x0)];
      const u32 hi = ks_base[w1*128 + (m ^ x1)];
      vwj[jj] = lo | (hi << 16);
    }
    u32x4 vw = { vwj[0], vwj[1], vwj[2], vwj[3] };
    const bf16x8 vfrag = __builtin_bit_cast(bf16x8, vw);
    f32x4 z = {0.f,0.f,0.f,0.f};
    o[nt] = MFMA(pa, vfrag, z);
  }
  __builtin_amdgcn_s_setprio(0);

  // ---- store (non-temporal: output is never re-read) ----
  float* orow[4];
#pragma unroll
  for (int r = 0; r < 4; ++r)
    orow[r] = ob + (size_t)(t0 + 4*g + r)*kH + hw0 + c;
#pragma unroll
  for (int nt = 0; nt < 8; ++nt)
#pragma unroll
    for (int r = 0; r < 4; ++r)
      __builtin_nontemporal_store(o[nt][r], &orow[r][16*nt]);
}

extern "C" void kernel_launch(void* const* d_in, const int* in_sizes, int n_in,
                              void* d_out, int out_size, void* d_ws, size_t ws_size,
                              hipStream_t stream) {
  const float* x = (const float*)d_in[0];
  float* out = (float*)d_out;
  hipLaunchKernelGGL(fenc_mfma, dim3(kBlocks), dim3(512), 0, stream, x, out);
}